// Round 5
// baseline (405.606 us; speedup 1.0000x reference)
//
#include <hip/hip_runtime.h>
#include <hip/hip_bf16.h>

#define N_ 4
#define T_ 4096
#define D_ 512
#define H_ 8
#define DH_ 64
#define NH_ 4
#define NB_ 64
#define CS_ 256
#define L_ 16384

typedef unsigned short u16;
typedef unsigned int u32;
typedef __attribute__((ext_vector_type(8))) short short8;
typedef __attribute__((ext_vector_type(8))) _Float16 half8;
typedef __attribute__((ext_vector_type(4))) float f32x4;
typedef __attribute__((ext_vector_type(2))) float f32x2;

__device__ __forceinline__ u16 f2bf(float x){
    union { float f; u32 u; } c; c.f = x;
    u32 u = c.u;
    u32 r = (u + 0x7FFFu + ((u >> 16) & 1u)) >> 16;
    return (u16)r;
}
__device__ __forceinline__ float bf2f(u16 b){
    union { u32 u; float f; } c; c.u = ((u32)b) << 16;
    return c.f;
}
__device__ __forceinline__ u16 f2h(float x){
    _Float16 h = (_Float16)x;
    u16 r; __builtin_memcpy(&r, &h, 2); return r;
}

// packed fp32 FMA: acc.{lo,hi} += a_scalar * b.{lo,hi}
// op_sel/op_sel_hi broadcast src0's lo (PK_LO) or hi (PK_HI) half to both
// result halves. NOTE (r4 data): half-rate on gfx950 (4 cyc) — the win vs
// scalar FMA is issue-slot economy, not pipe throughput.
#define PK_LO(acc, a, b) \
    asm("v_pk_fma_f32 %0, %1, %2, %0 op_sel:[0,0,0] op_sel_hi:[0,1,1]" \
        : "+v"(acc) : "v"(a), "v"(b))
#define PK_HI(acc, a, b) \
    asm("v_pk_fma_f32 %0, %1, %2, %0 op_sel:[1,0,0] op_sel_hi:[1,1,1]" \
        : "+v"(acc) : "v"(a), "v"(b))

// sVt bank-spread swizzle: low-3 bits vary with d>>3 (=l8 in staging) so a
// wave's 64 transpose-writes cover all 32 banks.
#define VSWZ(d) ((((d) >> 3) ^ ((d) & 7)))

// ---------------------------------------------------------------------------
// K0a: x -> f16 copy (for V MFMA path)
// ---------------------------------------------------------------------------
__global__ __launch_bounds__(256) void k_decXf(const float* __restrict__ x,
        u16* __restrict__ xf){
    int i = blockIdx.x * 256 + threadIdx.x;        // float4 index
    float4 v = ((const float4*)x)[i];
    ushort4 o;
    o.x = f2h(v.x); o.y = f2h(v.y); o.z = f2h(v.z); o.w = f2h(v.w);
    ((ushort4*)xf)[i] = o;
}

// ---------------------------------------------------------------------------
// K0b: transpose Wv -> wvt [512 n][512 k] f16
// ---------------------------------------------------------------------------
__global__ __launch_bounds__(256) void k_decWv(const float* __restrict__ Wv,
        u16* __restrict__ wvt){
    __shared__ float tile[32][33];
    const int tid = threadIdx.x;
    const int kt = blockIdx.x * 32, nt = blockIdx.y * 32;
    const int tx = tid & 31, ty = tid >> 5;
    #pragma unroll
    for (int i = 0; i < 4; ++i)
        tile[ty + i * 8][tx] = Wv[(size_t)(kt + ty + i * 8) * 512 + nt + tx];
    __syncthreads();
    #pragma unroll
    for (int i = 0; i < 4; ++i){
        int n = ty + i * 8;
        wvt[(size_t)(nt + n) * 512 + kt + tx] = f2h(tile[tx][n]);
    }
}

// ---------------------------------------------------------------------------
// K1a: Q = x@W_Q + b_Q  (fp32 VALU — exact-class for bucket argmax).
//      r3 geometry (512 thr, 128x128 tile, 8x4 frag, dbuf, 4 waves/SIMD)
//      + BK=32: half the barriers (16 vs 32) to cut the ~33% VALU-idle
//      barrier/drain stall. LDS 67.6KB -> still 2 blocks/CU (wave-capped).
//      Accumulation per output element (k ascending, fma) bit-identical.
//      Also emits Qbf (bf16 head-major) + qinv row norms for k_attn.
// ---------------------------------------------------------------------------
__global__ __launch_bounds__(512, 4) void k_q(const float* __restrict__ x,
        const float* __restrict__ Wq, const float* __restrict__ bq,
        float* __restrict__ Q, u16* __restrict__ Qbf, float* __restrict__ qinv){
    __shared__ float sA[2][32][132];  // [buf][k][m] transposed
    __shared__ float sB[2][32][132];  // [buf][k][n]
    const int tid = threadIdx.x;
    const int tx = tid & 31, ty = tid >> 5;     // frag: rows ty*8..+7, cols tx*4..+3
    const int mb = blockIdx.x * 128, nb = blockIdx.y * 128;

    f32x2 acc2[8][2];
    #pragma unroll
    for (int i = 0; i < 8; ++i){
        acc2[i][0] = (f32x2){0.f, 0.f};
        acc2[i][1] = (f32x2){0.f, 0.f};
    }

    // staging (BK=32): A = 128m x 32k -> 1024 float4, 2/thread (m, m+64);
    //                  B = 32k x 128n -> 1024 float4, 2/thread (k, k+16).
    const int mA = tid >> 3, kA = (tid & 7) * 4;
    const int kB = tid >> 5, cB = (tid & 31) * 4;
    const float* xp0 = &x[(size_t)(mb + mA) * 512 + kA];
    const float* xp1 = xp0 + (size_t)64 * 512;
    const float* wp0 = &Wq[(size_t)kB * 512 + nb + cB];
    const float* wp1 = wp0 + (size_t)16 * 512;

    float4 pa0 = *(const float4*)xp0;
    float4 pa1 = *(const float4*)xp1;
    float4 pb0 = *(const float4*)wp0;
    float4 pb1 = *(const float4*)wp1;

    for (int k0 = 0; k0 < 512; k0 += 32){
        const int p = (k0 >> 5) & 1;
        sA[p][kA + 0][mA] = pa0.x; sA[p][kA + 1][mA] = pa0.y;
        sA[p][kA + 2][mA] = pa0.z; sA[p][kA + 3][mA] = pa0.w;
        sA[p][kA + 0][64 + mA] = pa1.x; sA[p][kA + 1][64 + mA] = pa1.y;
        sA[p][kA + 2][64 + mA] = pa1.z; sA[p][kA + 3][64 + mA] = pa1.w;
        *(float4*)&sB[p][kB][cB] = pb0;
        *(float4*)&sB[p][kB + 16][cB] = pb1;
        __syncthreads();
        if (k0 < 480){
            pa0 = *(const float4*)(xp0 + k0 + 32);
            pa1 = *(const float4*)(xp1 + k0 + 32);
            pb0 = *(const float4*)(wp0 + (size_t)(k0 + 32) * 512);
            pb1 = *(const float4*)(wp1 + (size_t)(k0 + 32) * 512);
        }
        #pragma unroll
        for (int kk = 0; kk < 32; ++kk){
            float4 va0 = *(const float4*)&sA[p][kk][ty * 8];
            float4 va1 = *(const float4*)&sA[p][kk][ty * 8 + 4];
            float4 vb  = *(const float4*)&sB[p][kk][tx * 4];
            f32x2 a2[4], b2[2];
            a2[0] = (f32x2){va0.x, va0.y}; a2[1] = (f32x2){va0.z, va0.w};
            a2[2] = (f32x2){va1.x, va1.y}; a2[3] = (f32x2){va1.z, va1.w};
            b2[0] = (f32x2){vb.x, vb.y};   b2[1] = (f32x2){vb.z, vb.w};
            #pragma unroll
            for (int i = 0; i < 8; ++i){
                if (i & 1){
                    PK_HI(acc2[i][0], a2[i >> 1], b2[0]);
                    PK_HI(acc2[i][1], a2[i >> 1], b2[1]);
                } else {
                    PK_LO(acc2[i][0], a2[i >> 1], b2[0]);
                    PK_LO(acc2[i][1], a2[i >> 1], b2[1]);
                }
            }
        }
        // no trailing barrier: next iteration writes the other buffer
    }

    // epilogue: thread owns cols nb+tx*4..+3 (one head), rows ty*8..+7
    float4 vbq = *(const float4*)&bq[nb + tx * 4];
    const int h = blockIdx.y * 2 + (tx >> 4);
    const int d0 = (tx & 15) * 4;
    #pragma unroll
    for (int i = 0; i < 8; ++i){
        float o0 = acc2[i][0].x + vbq.x;
        float o1 = acc2[i][0].y + vbq.y;
        float o2 = acc2[i][1].x + vbq.z;
        float o3 = acc2[i][1].y + vbq.w;
        int m = mb + ty * 8 + i;
        int n = m >> 12, t = m & (T_ - 1);
        float4 q4; q4.x = o0; q4.y = o1; q4.z = o2; q4.w = o3;
        *(float4*)&Q[(size_t)m * 512 + nb + tx * 4] = q4;
        float ss = o0 * o0 + o1 * o1 + o2 * o2 + o3 * o3;
        #pragma unroll
        for (int s = 8; s >= 1; s >>= 1) ss += __shfl_xor(ss, s, 64);
        size_t rowb = (size_t)(h * N_ + n) * T_ + t;
        if ((tx & 15) == 0) qinv[rowb] = 1.f / (sqrtf(ss) + 1e-6f);
        ushort4 qb4;
        qb4.x = f2bf(o0); qb4.y = f2bf(o1); qb4.z = f2bf(o2); qb4.w = f2bf(o3);
        *(ushort4*)&Qbf[rowb * 64 + d0] = qb4;
    }
}

// ---------------------------------------------------------------------------
// K1b: V = x@W_V + b_V  via single-product f16 MFMA -> Vbf bf16 head-major.
//      (r3 version — r4's dbuf rewrite regressed ~12us, reverted.)
// ---------------------------------------------------------------------------
__global__ __launch_bounds__(256) void k_gemmV(const u16* __restrict__ xf,
        const u16* __restrict__ wvt, const float* __restrict__ bv,
        u16* __restrict__ Vbf){
    __shared__ __align__(16) u16 sA[128 * 40];
    __shared__ __align__(16) u16 sB[128 * 40];
    const int tid = threadIdx.x;
    const int mb = blockIdx.x * 128, nb = blockIdx.y * 128;
    const int w = tid >> 6, lane = tid & 63, quad = lane >> 4, cc = lane & 15;
    const int wm = (w & 1) * 64, wn = (w >> 1) * 64;
    f32x4 acc[4][4];
    #pragma unroll
    for (int i = 0; i < 4; ++i)
        #pragma unroll
        for (int j = 0; j < 4; ++j) acc[i][j] = (f32x4){0.f, 0.f, 0.f, 0.f};

    for (int k0 = 0; k0 < 512; k0 += 32){
        #pragma unroll
        for (int i = 0; i < 2; ++i){
            int idx = i * 256 + tid;               // 0..511
            int m = idx >> 2, ks = idx & 3;
            *(short8*)&sA[m * 40 + ks * 8] =
                *(const short8*)&xf[(size_t)(mb + m) * 512 + k0 + ks * 8];
            *(short8*)&sB[m * 40 + ks * 8] =
                *(const short8*)&wvt[(size_t)(nb + m) * 512 + k0 + ks * 8];
        }
        __syncthreads();
        half8 a[4], b[4];
        #pragma unroll
        for (int i = 0; i < 4; ++i){
            a[i] = *(const half8*)&sA[(wm + i * 16 + cc) * 40 + quad * 8];
            b[i] = *(const half8*)&sB[(wn + i * 16 + cc) * 40 + quad * 8];
        }
        #pragma unroll
        for (int i = 0; i < 4; ++i)
            #pragma unroll
            for (int j = 0; j < 4; ++j)
                acc[i][j] = __builtin_amdgcn_mfma_f32_16x16x32_f16(a[i], b[j], acc[i][j], 0, 0, 0);
        __syncthreads();
    }
    #pragma unroll
    for (int i = 0; i < 4; ++i)
        #pragma unroll
        for (int j = 0; j < 4; ++j){
            int c = nb + wn + j * 16 + cc;
            int hh = c >> 6, d = c & 63;
            float bi = bv[c];
            #pragma unroll
            for (int r = 0; r < 4; ++r){
                int m = mb + wm + i * 16 + quad * 4 + r;
                int n = m >> 12, t = m & (T_ - 1);
                Vbf[((size_t)(hh * N_ + n) * T_ + t) * 64 + d] = f2bf(acc[i][j][r] + bi);
            }
        }
}

// ---------------------------------------------------------------------------
// K2: rotations + argmax -> buckets[h][n][j*T + t]  (fp32, exact tie rules)
//     Rs re-laid in LDS as [f][i][jj] so rot reads are b128 and Q reads are
//     b64 f-pairs; packed FMA with PK_LO(f)/PK_HI(f+1) keeps accumulation
//     order (f ascending, one fma per f) bit-identical.
// ---------------------------------------------------------------------------
__global__ __launch_bounds__(256) void k_rot(const float* __restrict__ Q,
        const float* __restrict__ rot, int* __restrict__ buckets){
    const int tb = blockIdx.x * 32;
    const int n = blockIdx.y, h = blockIdx.z;
    const int hn = h * N_ + n;
    __shared__ float Rs[64 * 128];    // [f][i][jj]: f*128 + i*4 + jj
    __shared__ float Qs[32][64];
    const int tid = threadIdx.x;
    const float* rh = rot + (size_t)h * (64 * 128);   // [f][jj][i] contiguous
    for (int idx = tid; idx < 8192; idx += 256){
        int f = idx >> 7, rem = idx & 127, jj = rem >> 5, i2 = rem & 31;
        Rs[f * 128 + i2 * 4 + jj] = rh[idx];
    }
    for (int i = tid; i < 2048; i += 256){
        int t = i >> 6, f = i & 63;
        Qs[t][f] = Q[(size_t)(n * T_ + tb + t) * 512 + h * 64 + f];
    }
    __syncthreads();
    const int tx = tid & 31, tg = tid >> 5;   // tg: 8 groups of 4 t's
    f32x2 r2[4][2];                            // [tt][jj-pair]
    #pragma unroll
    for (int tt = 0; tt < 4; ++tt){
        r2[tt][0] = (f32x2){0.f, 0.f};
        r2[tt][1] = (f32x2){0.f, 0.f};
    }
    for (int f = 0; f < 64; f += 2){
        f32x2 qf[4];
        #pragma unroll
        for (int tt = 0; tt < 4; ++tt)
            qf[tt] = *(const f32x2*)&Qs[tg * 4 + tt][f];   // (q[f], q[f+1])
        float4 rv0 = *(const float4*)&Rs[f * 128 + tx * 4];
        float4 rv1 = *(const float4*)&Rs[(f + 1) * 128 + tx * 4];
        f32x2 b0[2], b1[2];
        b0[0] = (f32x2){rv0.x, rv0.y}; b0[1] = (f32x2){rv0.z, rv0.w};
        b1[0] = (f32x2){rv1.x, rv1.y}; b1[1] = (f32x2){rv1.z, rv1.w};
        #pragma unroll
        for (int tt = 0; tt < 4; ++tt){
            PK_LO(r2[tt][0], qf[tt], b0[0]);   // f   contribution
            PK_LO(r2[tt][1], qf[tt], b0[1]);
            PK_HI(r2[tt][0], qf[tt], b1[0]);   // f+1 contribution
            PK_HI(r2[tt][1], qf[tt], b1[1]);
        }
    }
    #pragma unroll
    for (int tt = 0; tt < 4; ++tt){
        #pragma unroll
        for (int jj = 0; jj < 4; ++jj){
            float rval = (jj < 2) ? r2[tt][0][jj] : r2[tt][1][jj - 2];
            // argmax over concat(r, -r); first-occurrence tie-break
            float bv = rval; int bi = tx;
            float nv = -bv;
            if (nv > bv){ bv = nv; bi = 32 + tx; }
            #pragma unroll
            for (int m = 16; m >= 1; m >>= 1){
                float ov = __shfl_xor(bv, m, 32);
                int   oi = __shfl_xor(bi, m, 32);
                if (ov > bv || (ov == bv && oi < bi)){ bv = ov; bi = oi; }
            }
            if (tx == 0){
                int t = tb + tg * 4 + tt;
                buckets[(size_t)hn * L_ + jj * T_ + t] = bi + jj * 64;
            }
        }
    }
}

// ---------------------------------------------------------------------------
// K3a: per-(hn,tile) 256-bin histogram. tile = 256 consecutive items.
// ---------------------------------------------------------------------------
__global__ __launch_bounds__(256) void k_hist(const int* __restrict__ buckets,
        int* __restrict__ hist){
    const int tile = blockIdx.x, hn = blockIdx.y;
    const int tid = threadIdx.x;
    __shared__ int h[256];
    h[tid] = 0;
    __syncthreads();
    int b = buckets[(size_t)hn * L_ + tile * 256 + tid];
    atomicAdd(&h[b], 1);
    __syncthreads();
    hist[((size_t)hn * 64 + tile) * 256 + tid] = h[tid];
}

// ---------------------------------------------------------------------------
// K3b: per-hn: in-place exclusive prefix of hist over tiles (per bucket),
//      then block scan of bucket totals -> bucketStart[hn][256]
// ---------------------------------------------------------------------------
__global__ __launch_bounds__(256) void k_scan(int* __restrict__ hist,
        int* __restrict__ bucketStart){
    const int hn = blockIdx.x;
    const int b = threadIdx.x;
    int* hh = hist + (size_t)hn * 64 * 256;
    int run = 0;
    for (int tl = 0; tl < 64; ++tl){
        int v = hh[tl * 256 + b];
        hh[tl * 256 + b] = run;      // exclusive within-bucket tile prefix
        run += v;
    }
    __shared__ int s[256];
    s[b] = run;
    __syncthreads();
    for (int off = 1; off < 256; off <<= 1){
        int add = (b >= off) ? s[b - off] : 0;
        __syncthreads();
        s[b] += add;
        __syncthreads();
    }
    bucketStart[hn * 256 + b] = s[b] - run;   // exclusive bucket start
}

// ---------------------------------------------------------------------------
// K3c: stable scatter: sticker[pos] = item index
// ---------------------------------------------------------------------------
__global__ __launch_bounds__(256) void k_scatter(const int* __restrict__ buckets,
        const int* __restrict__ offs, const int* __restrict__ bucketStart,
        int* __restrict__ sticker){
    const int tile = blockIdx.x, hn = blockIdx.y;
    const int tid = threadIdx.x;
    __shared__ int sb[256];
    const int i = tile * 256 + tid;
    const int b = buckets[(size_t)hn * L_ + i];
    sb[tid] = b;
    __syncthreads();
    int rank = 0;
    #pragma unroll 8
    for (int j = 0; j < 256; ++j){
        int v = sb[j];                         // broadcast read
        rank += (j < tid && v == b) ? 1 : 0;
    }
    int pos = bucketStart[hn * 256 + b]
            + offs[((size_t)hn * 64 + tile) * 256 + b]
            + rank;
    sticker[(size_t)hn * L_ + pos] = i;
}

// ---------------------------------------------------------------------------
// K4: chunked attention via MFMA. block = (chunk, n, h). 64 q x 128 k, DH=64
//     sP aliases sQ (dead after QK^T) -> ~34.5KB LDS -> 4 blocks/CU.
// ---------------------------------------------------------------------------
__global__ __launch_bounds__(256) void k_attn(const u16* __restrict__ Qbf,
        const u16* __restrict__ Vbf, const float* __restrict__ qinv,
        const int* __restrict__ buckets, const int* __restrict__ sticker,
        u16* __restrict__ o_hash, float* __restrict__ logit_hash){
    const int blk_c = blockIdx.x, n = blockIdx.y, h = blockIdx.z;
    const int hn = h * N_ + n;
    const int tid = threadIdx.x;
    const int w = tid >> 6, lane = tid & 63;
    const int quad = lane >> 4, cc = lane & 15;

    // XOR-swizzled bf16 tiles. sQP is sQ (rows = sorted positions, live
    // through QK^T) then re-used as sP (probs, live through PV) — both 16KB.
    __shared__ __align__(16) u16 sQP[128 * 64];
    __shared__ __align__(16) u16 sVt[64 * 128];   // row = d, col = key row (V^T)
    __shared__ int s_idx[128], s_buck[128], s_t[128];
    __shared__ float s_inv[128];
    __shared__ float s_lse[64];
    u16* const sQ = sQP;
    u16* const sP = sQP;

    if (tid < 128){
        int cprev = (blk_c + CS_ - 1) & (CS_ - 1);
        int pos = (tid < 64) ? blk_c * 64 + tid : cprev * 64 + (tid - 64);
        int idx = sticker[(size_t)hn * L_ + pos];
        s_idx[tid] = idx;
        s_buck[tid] = buckets[(size_t)hn * L_ + idx];
        int t = idx & (T_ - 1);
        s_t[tid] = t;
        s_inv[tid] = qinv[(size_t)hn * T_ + t] * 0.125f;   // exact pow2 fold
    }
    __syncthreads();

    // ---- stage Q rows (b128) and V transposed (scalar b16) ----
    const int r0 = tid >> 3, l8 = tid & 7;
    #pragma unroll
    for (int it = 0; it < 4; ++it){
        int r = it * 32 + r0;
        size_t gb = ((size_t)hn * T_ + s_t[r]) * 64 + l8 * 8;
        short8 qv = *(const short8*)&Qbf[gb];
        *(short8*)&sQ[r * 64 + ((l8 ^ (r & 7)) * 8)] = qv;
        short8 vv = *(const short8*)&Vbf[gb];
        #pragma unroll
        for (int i = 0; i < 8; ++i){
            int d = l8 * 8 + i;
            sVt[d * 128 + (((r >> 3) ^ VSWZ(d)) * 8) + (r & 7)] = (u16)vv[i];
        }
    }
    __syncthreads();

    // ---- QK^T: wave w -> q-tile w; 2 k-chunks x 8 k-tiles ----
    f32x4 dacc[8];
    #pragma unroll
    for (int j = 0; j < 8; ++j) dacc[j] = (f32x4){0.f, 0.f, 0.f, 0.f};
    const int qrow = w * 16 + cc;
    #pragma unroll
    for (int kc = 0; kc < 2; ++kc){
        short8 afrag = *(const short8*)&sQ[qrow * 64 + (((kc * 4 + quad) ^ (cc & 7)) * 8)];
        #pragma unroll
        for (int kt = 0; kt < 8; ++kt){
            int krow = kt * 16 + cc;
            short8 bfrag = *(const short8*)&sQ[krow * 64 + (((kc * 4 + quad) ^ (cc & 7)) * 8)];
            dacc[kt] = __builtin_amdgcn_mfma_f32_16x16x32_bf16(afrag, bfrag, dacc[kt], 0, 0, 0);
        }
    }

    // ---- scale + masks + row softmax (rows: q = w*16 + quad*4 + reg) ----
    int bq[4], tq[4];
    #pragma unroll
    for (int r = 0; r < 4; ++r){
        int q = w * 16 + quad * 4 + r;
        bq[r] = s_buck[q]; tq[r] = s_t[q];
    }
    float mrow[4] = {-1e30f, -1e30f, -1e30f, -1e30f};
    #pragma unroll
    for (int kt = 0; kt < 8; ++kt){
        int kk = kt * 16 + cc;
        float inv = s_inv[kk];
        int bk = s_buck[kk], tk = s_t[kk];
        #pragma unroll
        for (int r = 0; r < 4; ++r){
            float d = dacc[kt][r] * inv;
            if (bk != bq[r]) d = -1e9f;
            if (tk == tq[r]) d = -1e-5f;
            dacc[kt][r] = d;
            mrow[r] = fmaxf(mrow[r], d);
        }
    }
    #pragma unroll
    for (int r = 0; r < 4; ++r)
        #pragma unroll
        for (int m = 8; m >= 1; m >>= 1)
            mrow[r] = fmaxf(mrow[r], __shfl_xor(mrow[r], m, 64));
    // exp once: keep p = exp(d - m) in dacc, sum it
    float srow[4] = {0.f, 0.f, 0.f, 0.f};
    #pragma unroll
    for (int kt = 0; kt < 8; ++kt)
        #pragma unroll
        for (int r = 0; r < 4; ++r){
            float e = __expf(dacc[kt][r] - mrow[r]);
            dacc[kt][r] = e;
            srow[r] += e;
        }
    #pragma unroll
    for (int r = 0; r < 4; ++r)
        #pragma unroll
        for (int m = 8; m >= 1; m >>= 1)
            srow[r] += __shfl_xor(srow[r], m, 64);
    float lse[4], pscale[4];
    #pragma unroll
    for (int r = 0; r < 4; ++r){
        lse[r] = mrow[r] + __logf(srow[r]);
        pscale[r] = 1.f / srow[r];
    }
    if (cc == 0){
        #pragma unroll
        for (int r = 0; r < 4; ++r) s_lse[w * 16 + quad * 4 + r] = lse[r];
    }

    // all waves' QK^T reads of sQ must complete before sP overwrites it;
    // barrier placed after softmax so that VALU overlaps slower waves' MFMA.
    __syncthreads();

    // ---- probs -> sP (C-layout scatter into swizzled A-layout tile) ----
    #pragma unroll
    for (int kt = 0; kt < 8; ++kt){
        int kk = kt * 16 + cc;
        #pragma unroll
        for (int r = 0; r < 4; ++r){
            int q = w * 16 + quad * 4 + r;
            sP[q * 128 + (((kk >> 3) ^ (q & 15)) * 8) + (kk & 7)] =
                f2bf(dacc[kt][r] * pscale[r]);
        }
    }
    __syncthreads();

    // ---- PV: wave w -> q-tile w; 4 k-chunks x 4 n-tiles ----
    f32x4 oacc[4];
    #pragma unroll
    for (int j = 0; j < 4; ++j) oacc[j] = (f32x4){0.f, 0.f, 0.f, 0.f};
    #pragma unroll
    for (int kc = 0; kc < 4; ++kc){
        short8 afrag = *(const short8*)&sP[qrow * 128 + (((kc * 4 + quad) ^ cc) * 8)];
        #pragma unroll
        for (int nt = 0; nt < 4; ++nt){
            int d = nt * 16 + cc;
            short8 bfrag = *(const short8*)&sVt[d * 128 + (((kc * 4 + quad) ^ VSWZ(d)) * 8)];
            oacc[nt] = __builtin_amdgcn_mfma_f32_16x16x32_bf16(afrag, bfrag, oacc[nt], 0, 0, 0);
        }
    }

    // ---- epilogue: scatter o (bf16) and logits to per-hash buffers ----
    #pragma unroll
    for (int r = 0; r < 4; ++r){
        int q = w * 16 + quad * 4 + r;
        int si = s_idx[q];
        int jj = si >> 12; int t = si & (T_ - 1);
        size_t base = ((size_t)(hn * NH_ + jj) * T_ + t) * 64;
        #pragma unroll
        for (int nt = 0; nt < 4; ++nt)
            o_hash[base + nt * 16 + cc] = f2bf(oacc[nt][r]);
    }
    if (tid < 64){
        int si = s_idx[tid]; int jj = si >> 12; int t = si & (T_ - 1);
        logit_hash[(size_t)(hn * NH_ + jj) * T_ + t] = s_lse[tid];
    }
}

// ---------------------------------------------------------------------------
// K5: combine over NH hash rounds per head + fused LayerNorm. block = (t,n)
// ---------------------------------------------------------------------------
__global__ __launch_bounds__(256) void k_comb(const u16* __restrict__ o_hash,
        const float* __restrict__ logit_hash, const float* __restrict__ gamma,
        const float* __restrict__ beta, float* __restrict__ out){
    const int t = blockIdx.x, n = blockIdx.y;
    const int tid = threadIdx.x;
    __shared__ float s_pw[32];
    __shared__ float s_x[512];
    __shared__ float s_red[8];
    __shared__ float s_mu, s_rs;
    if (tid < 32){
        int h = tid >> 2, j = tid & 3;
        s_pw[tid] = logit_hash[(size_t)((h * N_ + n) * NH_ + j) * T_ + t];
    }
    __syncthreads();
    if (tid < 8){
        int h = tid;
        float m = -1e30f;
        #pragma unroll
        for (int j = 0; j < 4; ++j) m = fmaxf(m, s_pw[h * 4 + j]);
        float l = 0.f;
        #pragma unroll
        for (int j = 0; j < 4; ++j) l += __expf(s_pw[h * 4 + j] - m);
        float ls = m + __logf(l);
        #pragma unroll
        for (int j = 0; j < 4; ++j) s_pw[h * 4 + j] = __expf(s_pw[h * 4 + j] - ls);
    }
    __syncthreads();
    float va[2];
    #pragma unroll
    for (int i = 0; i < 2; ++i){
        int cidx = tid + i * 256;
        int h = cidx >> 6, d = cidx & 63;
        size_t base = (size_t)((h * N_ + n) * NH_) * T_ * 64;
        float acc = 0.f;
        #pragma unroll
        for (int j = 0; j < 4; ++j)
            acc += s_pw[h * 4 + j] * bf2f(o_hash[base + ((size_t)j * T_ + t) * 64 + d]);
        s_x[cidx] = acc; va[i] = acc;
    }
    float s1 = va[0] + va[1];
    float s2 = va[0] * va[0] + va[1] * va[1];
    #pragma unroll
    for (int m = 32; m >= 1; m >>= 1){
        s1 += __shfl_xor(s1, m, 64);
        s2 += __shfl_xor(s2, m, 64);
    }
    const int lane = tid & 63, w = tid >> 6;
    if (lane == 0){ s_red[w] = s1; s_red[4 + w] = s2; }
    __syncthreads();
    if (tid == 0){
        float S1 = s_red[0] + s_red[1] + s_red[2] + s_red[3];
        float S2 = s_red[4] + s_red[5] + s_red[6] + s_red[7];
        float mu = S1 / 512.f;
        float var = S2 / 512.f - mu * mu;
        s_mu = mu; s_rs = 1.f / sqrtf(var + 1e-3f);
    }
    __syncthreads();
    #pragma unroll
    for (int i = 0; i < 2; ++i){
        int cidx = tid + i * 256;
        out[((size_t)(n * T_ + t)) * 512 + cidx] =
            gamma[cidx] * (s_x[cidx] - s_mu) * s_rs + beta[cidx];
    }
}

// ---------------------------------------------------------------------------
extern "C" void kernel_launch(void* const* d_in, const int* in_sizes, int n_in,
                              void* d_out, int out_size, void* d_ws, size_t ws_size,
                              hipStream_t stream){
    const float* x     = (const float*)d_in[0];
    const float* Wq    = (const float*)d_in[1];
    const float* bq    = (const float*)d_in[2];
    const float* Wv    = (const float*)d_in[3];
    const float* bv    = (const float*)d_in[4];
    const float* gamma = (const float*)d_in[5];
    const float* beta  = (const float*)d_in[6];
    const float* rot   = (const float*)d_in[7];
    char* ws = (char*)d_ws;
    // workspace layout (<= ~140.5 MB). Time-disjoint overlap:
    //   Q fp32 [0,33.5MB) is dead after k_rot; o_hash [0,67.1MB) is written
    //   only by k_attn (strictly later in stream order).
    float* Q        = (float*)(ws + 0);               // 33,554,432 B (k_q..k_rot)
    u16*   o_hash   = (u16*)  (ws + 0);               // 67,108,864 B (k_attn..k_comb)
    u16*   Qbf      = (u16*)  (ws + 67108864);        // 16,777,216 B
    u16*   Vbf      = (u16*)  (ws + 83886080);        // 16,777,216 B
    float* qinv     = (float*)(ws + 100663296);       //    524,288 B
    int*   buckets  = (int*)  (ws + 101187584);       //  2,097,152 B
    int*   sticker  = (int*)  (ws + 103284736);       //  2,097,152 B
    float* logit    = (float*)(ws + 105381888);       //  2,097,152 B
    int*   hist     = (int*)  (ws + 107479040);       //  2,097,152 B
    int*   bstart   = (int*)  (ws + 109576192);       //     32,768 B
    u16*   xf       = (u16*)  (ws + 109608960);       // 16,777,216 B (dead after k_gemmV)
    u16*   wvt      = (u16*)  (ws + 126386176);       //    524,288 B

    hipLaunchKernelGGL(k_decXf,   dim3(8192),       dim3(256), 0, stream,
                       x, xf);
    hipLaunchKernelGGL(k_decWv,   dim3(16, 16),     dim3(256), 0, stream,
                       Wv, wvt);
    hipLaunchKernelGGL(k_gemmV,   dim3(128, 4),     dim3(256), 0, stream,
                       xf, wvt, bv, Vbf);
    hipLaunchKernelGGL(k_q,       dim3(128, 4),     dim3(512), 0, stream,
                       x, Wq, bq, Q, Qbf, qinv);
    hipLaunchKernelGGL(k_rot,     dim3(128, 4, 8),  dim3(256), 0, stream,
                       Q, rot, buckets);
    hipLaunchKernelGGL(k_hist,    dim3(64, 32),     dim3(256), 0, stream,
                       buckets, hist);
    hipLaunchKernelGGL(k_scan,    dim3(32),         dim3(256), 0, stream,
                       hist, bstart);
    hipLaunchKernelGGL(k_scatter, dim3(64, 32),     dim3(256), 0, stream,
                       buckets, hist, bstart, sticker);
    hipLaunchKernelGGL(k_attn,    dim3(256, 4, 8),  dim3(256), 0, stream,
                       Qbf, Vbf, qinv, buckets, sticker, o_hash, logit);
    hipLaunchKernelGGL(k_comb,    dim3(4096, 4),    dim3(256), 0, stream,
                       o_hash, logit, gamma, beta, (float*)d_out);
}

// Round 6
// 392.089 us; speedup vs baseline: 1.0345x; 1.0345x over previous
//
#include <hip/hip_runtime.h>
#include <hip/hip_bf16.h>

#define N_ 4
#define T_ 4096
#define D_ 512
#define H_ 8
#define DH_ 64
#define NH_ 4
#define NB_ 64
#define CS_ 256
#define L_ 16384

typedef unsigned short u16;
typedef unsigned int u32;
typedef __attribute__((ext_vector_type(8))) short short8;
typedef __attribute__((ext_vector_type(8))) _Float16 half8;
typedef __attribute__((ext_vector_type(4))) float f32x4;
typedef __attribute__((ext_vector_type(2))) float f32x2;

__device__ __forceinline__ u16 f2bf(float x){
    union { float f; u32 u; } c; c.f = x;
    u32 u = c.u;
    u32 r = (u + 0x7FFFu + ((u >> 16) & 1u)) >> 16;
    return (u16)r;
}
__device__ __forceinline__ float bf2f(u16 b){
    union { u32 u; float f; } c; c.u = ((u32)b) << 16;
    return c.f;
}
__device__ __forceinline__ u16 f2h(float x){
    _Float16 h = (_Float16)x;
    u16 r; __builtin_memcpy(&r, &h, 2); return r;
}

// packed fp32 FMA: acc.{lo,hi} += a_scalar * b.{lo,hi}
// op_sel/op_sel_hi broadcast src0's lo (PK_LO) or hi (PK_HI) half to both
// result halves. NOTE (r4 data): half-rate on gfx950 (4 cyc) — the win vs
// scalar FMA is issue-slot economy, not pipe throughput.
#define PK_LO(acc, a, b) \
    asm("v_pk_fma_f32 %0, %1, %2, %0 op_sel:[0,0,0] op_sel_hi:[0,1,1]" \
        : "+v"(acc) : "v"(a), "v"(b))
#define PK_HI(acc, a, b) \
    asm("v_pk_fma_f32 %0, %1, %2, %0 op_sel:[1,0,0] op_sel_hi:[1,1,1]" \
        : "+v"(acc) : "v"(a), "v"(b))

// sVt bank-spread swizzle: low-3 bits vary with d>>3 (=l8 in staging) so a
// wave's 64 transpose-writes cover all 32 banks.
#define VSWZ(d) ((((d) >> 3) ^ ((d) & 7)))

// ---------------------------------------------------------------------------
// K0a: x -> f16 copy (for V MFMA path)
// ---------------------------------------------------------------------------
__global__ __launch_bounds__(256) void k_decXf(const float* __restrict__ x,
        u16* __restrict__ xf){
    int i = blockIdx.x * 256 + threadIdx.x;        // float4 index
    float4 v = ((const float4*)x)[i];
    ushort4 o;
    o.x = f2h(v.x); o.y = f2h(v.y); o.z = f2h(v.z); o.w = f2h(v.w);
    ((ushort4*)xf)[i] = o;
}

// ---------------------------------------------------------------------------
// K0b: transpose Wv -> wvt [512 n][512 k] f16
// ---------------------------------------------------------------------------
__global__ __launch_bounds__(256) void k_decWv(const float* __restrict__ Wv,
        u16* __restrict__ wvt){
    __shared__ float tile[32][33];
    const int tid = threadIdx.x;
    const int kt = blockIdx.x * 32, nt = blockIdx.y * 32;
    const int tx = tid & 31, ty = tid >> 5;
    #pragma unroll
    for (int i = 0; i < 4; ++i)
        tile[ty + i * 8][tx] = Wv[(size_t)(kt + ty + i * 8) * 512 + nt + tx];
    __syncthreads();
    #pragma unroll
    for (int i = 0; i < 4; ++i){
        int n = ty + i * 8;
        wvt[(size_t)(nt + n) * 512 + kt + tx] = f2h(tile[tx][n]);
    }
}

// ---------------------------------------------------------------------------
// K1a (FUSED): Q = x@W_Q + b_Q, then rotations + bucket argmax, in one
//      kernel. The 128x128 tile = 128 rows x 2 complete heads, so the
//      rotation needs no cross-block data. Eliminates the fp32 Q buffer
//      (33.5MB write + 33.5MB read) and the separate k_rot dispatch; the
//      rotation VALU/LDS work fills the main loop's idle issue slots.
//      Main GEMM loop: r3-proven BK=16, 512 thr, 8x4 frag, dbuf, single
//      barrier/panel. Rotation replicates k_rot's exact fp32 fma chain
//      (f ascending, PK_LO/PK_HI pairing) and (max, min-index) tie-break
//      -> buckets bit-identical to the previous 2-kernel pipeline.
//      LDS: dbuf 33.8KB aliased by Qs[64][132] (33.8KB) + Rs 32KB = 66.6KB
//      -> 2 blocks/CU, 4 waves/SIMD (unchanged).
// ---------------------------------------------------------------------------
__global__ __launch_bounds__(512, 4) void k_q(const float* __restrict__ x,
        const float* __restrict__ Wq, const float* __restrict__ bq,
        const float* __restrict__ rot, u16* __restrict__ Qbf,
        float* __restrict__ qinv, int* __restrict__ buckets){
    // union LDS: [0,8448) floats = dbuf sA|sB  OR  Qs[64][132];
    //            [8448,16640) floats = Rs (rotation matrix, one head)
    __shared__ __align__(16) float uLDS[16640];   // 66,560 B
    typedef float (*panel_t)[16][132];
    panel_t sA = (panel_t)uLDS;                   // sA[p][k][m]
    panel_t sB = (panel_t)(uLDS + 4224);          // sB[p][k][n]
    typedef float (*qs_t)[132];
    qs_t Qs = (qs_t)uLDS;                         // Qs[lt][col]
    float* Rs = uLDS + 8448;                      // Rs[f*128 + i*4 + jj]

    const int tid = threadIdx.x;
    const int tx = tid & 31, ty = tid >> 5;   // frag: rows ty*8..+7, cols tx*4..+3
    const int mb = blockIdx.x * 128, nb = blockIdx.y * 128;
    const int h0 = blockIdx.y * 2;

    f32x2 acc2[8][2];
    #pragma unroll
    for (int i = 0; i < 8; ++i){
        acc2[i][0] = (f32x2){0.f, 0.f};
        acc2[i][1] = (f32x2){0.f, 0.f};
    }

    // staging: each thread loads exactly one float4 of A and one of B
    const int mA = tid >> 2, kA = (tid & 3) * 4;
    const int kB = tid >> 5, cB = (tid & 31) * 4;
    const float* xp = &x[(size_t)(mb + mA) * 512 + kA];
    const float* wp = &Wq[(size_t)kB * 512 + nb + cB];

    float4 pa = *(const float4*)xp;
    float4 pb = *(const float4*)wp;

    for (int k0 = 0; k0 < 512; k0 += 16){
        const int p = (k0 >> 4) & 1;
        sA[p][kA + 0][mA] = pa.x; sA[p][kA + 1][mA] = pa.y;
        sA[p][kA + 2][mA] = pa.z; sA[p][kA + 3][mA] = pa.w;
        *(float4*)&sB[p][kB][cB] = pb;
        __syncthreads();
        if (k0 < 496){
            pa = *(const float4*)(xp + k0 + 16);
            pb = *(const float4*)(wp + (size_t)(k0 + 16) * 512);
        }
        #pragma unroll
        for (int kk = 0; kk < 16; ++kk){
            float4 va0 = *(const float4*)&sA[p][kk][ty * 8];
            float4 va1 = *(const float4*)&sA[p][kk][ty * 8 + 4];
            float4 vb  = *(const float4*)&sB[p][kk][tx * 4];
            f32x2 a2[4], b2[2];
            a2[0] = (f32x2){va0.x, va0.y}; a2[1] = (f32x2){va0.z, va0.w};
            a2[2] = (f32x2){va1.x, va1.y}; a2[3] = (f32x2){va1.z, va1.w};
            b2[0] = (f32x2){vb.x, vb.y};   b2[1] = (f32x2){vb.z, vb.w};
            #pragma unroll
            for (int i = 0; i < 8; ++i){
                if (i & 1){
                    PK_HI(acc2[i][0], a2[i >> 1], b2[0]);
                    PK_HI(acc2[i][1], a2[i >> 1], b2[1]);
                } else {
                    PK_LO(acc2[i][0], a2[i >> 1], b2[0]);
                    PK_LO(acc2[i][1], a2[i >> 1], b2[1]);
                }
            }
        }
        // no trailing barrier: next iteration writes the other buffer
    }

    // ---- bias in place: acc2 now holds final Q values ----
    float4 vbq = *(const float4*)&bq[nb + tx * 4];
    #pragma unroll
    for (int i = 0; i < 8; ++i){
        acc2[i][0].x += vbq.x; acc2[i][0].y += vbq.y;
        acc2[i][1].x += vbq.z; acc2[i][1].y += vbq.w;
    }

    // ---- global epilogue writes (Qbf + qinv); issued before rotation so
    //      the stores fly underneath the rotation compute ----
    {
        const int h = h0 + (tx >> 4);
        const int d0 = (tx & 15) * 4;
        #pragma unroll
        for (int i = 0; i < 8; ++i){
            float o0 = acc2[i][0].x, o1 = acc2[i][0].y;
            float o2 = acc2[i][1].x, o3 = acc2[i][1].y;
            int m = mb + ty * 8 + i;
            int n = m >> 12, t = m & (T_ - 1);
            float ss = o0 * o0 + o1 * o1 + o2 * o2 + o3 * o3;
            #pragma unroll
            for (int s = 8; s >= 1; s >>= 1) ss += __shfl_xor(ss, s, 64);
            size_t rowb = (size_t)(h * N_ + n) * T_ + t;
            if ((tx & 15) == 0) qinv[rowb] = 1.f / (sqrtf(ss) + 1e-6f);
            ushort4 qb4;
            qb4.x = f2bf(o0); qb4.y = f2bf(o1); qb4.z = f2bf(o2); qb4.w = f2bf(o3);
            *(ushort4*)&Qbf[rowb * 64 + d0] = qb4;
        }
    }

    // ---- rotation + argmax (replaces k_rot) ----
    __syncthreads();   // main-loop LDS reads done; union region reusable
    const int gi = tid & 31, gg = tid >> 5;   // 16 groups x 4 rows = 64 rows
    #pragma unroll
    for (int chunk = 0; chunk < 2; ++chunk){
        // stage Qs rows [chunk*64, chunk*64+64) from registers
        if ((ty >> 3) == chunk){
            const int lt0 = (ty & 7) * 8;
            #pragma unroll
            for (int i = 0; i < 8; ++i){
                float4 q4;
                q4.x = acc2[i][0].x; q4.y = acc2[i][0].y;
                q4.z = acc2[i][1].x; q4.w = acc2[i][1].y;
                *(float4*)&Qs[lt0 + i][tx * 4] = q4;
            }
        }
        #pragma unroll
        for (int head = 0; head < 2; ++head){
            // stage Rs: re-lay rot[h][f][jj][i] -> Rs[f][i][jj]
            const float* rh = rot + (size_t)(h0 + head) * 8192;
            for (int idx = tid; idx < 8192; idx += 512){
                int f = idx >> 7, rem = idx & 127, jj = rem >> 5, i2 = rem & 31;
                Rs[f * 128 + i2 * 4 + jj] = rh[idx];
            }
            __syncthreads();
            // exact k_rot accumulation: per (row, i=gi, jj) chain over f
            f32x2 r2[4][2];
            #pragma unroll
            for (int tt = 0; tt < 4; ++tt){
                r2[tt][0] = (f32x2){0.f, 0.f};
                r2[tt][1] = (f32x2){0.f, 0.f};
            }
            for (int f = 0; f < 64; f += 2){
                f32x2 qf[4];
                #pragma unroll
                for (int tt = 0; tt < 4; ++tt)
                    qf[tt] = *(const f32x2*)&Qs[gg * 4 + tt][head * 64 + f];
                float4 rv0 = *(const float4*)&Rs[f * 128 + gi * 4];
                float4 rv1 = *(const float4*)&Rs[(f + 1) * 128 + gi * 4];
                f32x2 b0[2], b1[2];
                b0[0] = (f32x2){rv0.x, rv0.y}; b0[1] = (f32x2){rv0.z, rv0.w};
                b1[0] = (f32x2){rv1.x, rv1.y}; b1[1] = (f32x2){rv1.z, rv1.w};
                #pragma unroll
                for (int tt = 0; tt < 4; ++tt){
                    PK_LO(r2[tt][0], qf[tt], b0[0]);   // f   contribution
                    PK_LO(r2[tt][1], qf[tt], b0[1]);
                    PK_HI(r2[tt][0], qf[tt], b1[0]);   // f+1 contribution
                    PK_HI(r2[tt][1], qf[tt], b1[1]);
                }
            }
            #pragma unroll
            for (int tt = 0; tt < 4; ++tt){
                #pragma unroll
                for (int jj = 0; jj < 4; ++jj){
                    float rval = (jj < 2) ? r2[tt][0][jj] : r2[tt][1][jj - 2];
                    // argmax over concat(r, -r); first-occurrence tie-break
                    float bv = rval; int bi = gi;
                    float nv = -bv;
                    if (nv > bv){ bv = nv; bi = 32 + gi; }
                    #pragma unroll
                    for (int m = 16; m >= 1; m >>= 1){
                        float ov = __shfl_xor(bv, m, 32);
                        int   oi = __shfl_xor(bi, m, 32);
                        if (ov > bv || (ov == bv && oi < bi)){ bv = ov; bi = oi; }
                    }
                    if (gi == 0){
                        int m = mb + chunk * 64 + gg * 4 + tt;
                        int nn = m >> 12, t = m & (T_ - 1);
                        buckets[(size_t)((h0 + head) * N_ + nn) * L_ + jj * T_ + t]
                            = bi + jj * 64;
                    }
                }
            }
            __syncthreads();   // compute done before next Rs/Qs overwrite
        }
    }
}

// ---------------------------------------------------------------------------
// K1b: V = x@W_V + b_V  via single-product f16 MFMA -> Vbf bf16 head-major.
// ---------------------------------------------------------------------------
__global__ __launch_bounds__(256) void k_gemmV(const u16* __restrict__ xf,
        const u16* __restrict__ wvt, const float* __restrict__ bv,
        u16* __restrict__ Vbf){
    __shared__ __align__(16) u16 sA[128 * 40];
    __shared__ __align__(16) u16 sB[128 * 40];
    const int tid = threadIdx.x;
    const int mb = blockIdx.x * 128, nb = blockIdx.y * 128;
    const int w = tid >> 6, lane = tid & 63, quad = lane >> 4, cc = lane & 15;
    const int wm = (w & 1) * 64, wn = (w >> 1) * 64;
    f32x4 acc[4][4];
    #pragma unroll
    for (int i = 0; i < 4; ++i)
        #pragma unroll
        for (int j = 0; j < 4; ++j) acc[i][j] = (f32x4){0.f, 0.f, 0.f, 0.f};

    for (int k0 = 0; k0 < 512; k0 += 32){
        #pragma unroll
        for (int i = 0; i < 2; ++i){
            int idx = i * 256 + tid;               // 0..511
            int m = idx >> 2, ks = idx & 3;
            *(short8*)&sA[m * 40 + ks * 8] =
                *(const short8*)&xf[(size_t)(mb + m) * 512 + k0 + ks * 8];
            *(short8*)&sB[m * 40 + ks * 8] =
                *(const short8*)&wvt[(size_t)(nb + m) * 512 + k0 + ks * 8];
        }
        __syncthreads();
        half8 a[4], b[4];
        #pragma unroll
        for (int i = 0; i < 4; ++i){
            a[i] = *(const half8*)&sA[(wm + i * 16 + cc) * 40 + quad * 8];
            b[i] = *(const half8*)&sB[(wn + i * 16 + cc) * 40 + quad * 8];
        }
        #pragma unroll
        for (int i = 0; i < 4; ++i)
            #pragma unroll
            for (int j = 0; j < 4; ++j)
                acc[i][j] = __builtin_amdgcn_mfma_f32_16x16x32_f16(a[i], b[j], acc[i][j], 0, 0, 0);
        __syncthreads();
    }
    #pragma unroll
    for (int i = 0; i < 4; ++i)
        #pragma unroll
        for (int j = 0; j < 4; ++j){
            int c = nb + wn + j * 16 + cc;
            int hh = c >> 6, d = c & 63;
            float bi = bv[c];
            #pragma unroll
            for (int r = 0; r < 4; ++r){
                int m = mb + wm + i * 16 + quad * 4 + r;
                int n = m >> 12, t = m & (T_ - 1);
                Vbf[((size_t)(hh * N_ + n) * T_ + t) * 64 + d] = f2bf(acc[i][j][r] + bi);
            }
        }
}

// ---------------------------------------------------------------------------
// K3a: per-(hn,tile) 256-bin histogram. tile = 256 consecutive items.
// ---------------------------------------------------------------------------
__global__ __launch_bounds__(256) void k_hist(const int* __restrict__ buckets,
        int* __restrict__ hist){
    const int tile = blockIdx.x, hn = blockIdx.y;
    const int tid = threadIdx.x;
    __shared__ int h[256];
    h[tid] = 0;
    __syncthreads();
    int b = buckets[(size_t)hn * L_ + tile * 256 + tid];
    atomicAdd(&h[b], 1);
    __syncthreads();
    hist[((size_t)hn * 64 + tile) * 256 + tid] = h[tid];
}

// ---------------------------------------------------------------------------
// K3b: per-hn: in-place exclusive prefix of hist over tiles (per bucket),
//      then block scan of bucket totals -> bucketStart[hn][256]
// ---------------------------------------------------------------------------
__global__ __launch_bounds__(256) void k_scan(int* __restrict__ hist,
        int* __restrict__ bucketStart){
    const int hn = blockIdx.x;
    const int b = threadIdx.x;
    int* hh = hist + (size_t)hn * 64 * 256;
    int run = 0;
    for (int tl = 0; tl < 64; ++tl){
        int v = hh[tl * 256 + b];
        hh[tl * 256 + b] = run;      // exclusive within-bucket tile prefix
        run += v;
    }
    __shared__ int s[256];
    s[b] = run;
    __syncthreads();
    for (int off = 1; off < 256; off <<= 1){
        int add = (b >= off) ? s[b - off] : 0;
        __syncthreads();
        s[b] += add;
        __syncthreads();
    }
    bucketStart[hn * 256 + b] = s[b] - run;   // exclusive bucket start
}

// ---------------------------------------------------------------------------
// K3c: stable scatter: sticker[pos] = item index
// ---------------------------------------------------------------------------
__global__ __launch_bounds__(256) void k_scatter(const int* __restrict__ buckets,
        const int* __restrict__ offs, const int* __restrict__ bucketStart,
        int* __restrict__ sticker){
    const int tile = blockIdx.x, hn = blockIdx.y;
    const int tid = threadIdx.x;
    __shared__ int sb[256];
    const int i = tile * 256 + tid;
    const int b = buckets[(size_t)hn * L_ + i];
    sb[tid] = b;
    __syncthreads();
    int rank = 0;
    #pragma unroll 8
    for (int j = 0; j < 256; ++j){
        int v = sb[j];                         // broadcast read
        rank += (j < tid && v == b) ? 1 : 0;
    }
    int pos = bucketStart[hn * 256 + b]
            + offs[((size_t)hn * 64 + tile) * 256 + b]
            + rank;
    sticker[(size_t)hn * L_ + pos] = i;
}

// ---------------------------------------------------------------------------
// K4: chunked attention via MFMA. block = (chunk, n, h). 64 q x 128 k, DH=64
//     sP aliases sQ (dead after QK^T) -> ~34.5KB LDS -> 4 blocks/CU.
// ---------------------------------------------------------------------------
__global__ __launch_bounds__(256) void k_attn(const u16* __restrict__ Qbf,
        const u16* __restrict__ Vbf, const float* __restrict__ qinv,
        const int* __restrict__ buckets, const int* __restrict__ sticker,
        u16* __restrict__ o_hash, float* __restrict__ logit_hash){
    const int blk_c = blockIdx.x, n = blockIdx.y, h = blockIdx.z;
    const int hn = h * N_ + n;
    const int tid = threadIdx.x;
    const int w = tid >> 6, lane = tid & 63;
    const int quad = lane >> 4, cc = lane & 15;

    // XOR-swizzled bf16 tiles. sQP is sQ (rows = sorted positions, live
    // through QK^T) then re-used as sP (probs, live through PV) — both 16KB.
    __shared__ __align__(16) u16 sQP[128 * 64];
    __shared__ __align__(16) u16 sVt[64 * 128];   // row = d, col = key row (V^T)
    __shared__ int s_idx[128], s_buck[128], s_t[128];
    __shared__ float s_inv[128];
    __shared__ float s_lse[64];
    u16* const sQ = sQP;
    u16* const sP = sQP;

    if (tid < 128){
        int cprev = (blk_c + CS_ - 1) & (CS_ - 1);
        int pos = (tid < 64) ? blk_c * 64 + tid : cprev * 64 + (tid - 64);
        int idx = sticker[(size_t)hn * L_ + pos];
        s_idx[tid] = idx;
        s_buck[tid] = buckets[(size_t)hn * L_ + idx];
        int t = idx & (T_ - 1);
        s_t[tid] = t;
        s_inv[tid] = qinv[(size_t)hn * T_ + t] * 0.125f;   // exact pow2 fold
    }
    __syncthreads();

    // ---- stage Q rows (b128) and V transposed (scalar b16) ----
    const int r0 = tid >> 3, l8 = tid & 7;
    #pragma unroll
    for (int it = 0; it < 4; ++it){
        int r = it * 32 + r0;
        size_t gb = ((size_t)hn * T_ + s_t[r]) * 64 + l8 * 8;
        short8 qv = *(const short8*)&Qbf[gb];
        *(short8*)&sQ[r * 64 + ((l8 ^ (r & 7)) * 8)] = qv;
        short8 vv = *(const short8*)&Vbf[gb];
        #pragma unroll
        for (int i = 0; i < 8; ++i){
            int d = l8 * 8 + i;
            sVt[d * 128 + (((r >> 3) ^ VSWZ(d)) * 8) + (r & 7)] = (u16)vv[i];
        }
    }
    __syncthreads();

    // ---- QK^T: wave w -> q-tile w; 2 k-chunks x 8 k-tiles ----
    f32x4 dacc[8];
    #pragma unroll
    for (int j = 0; j < 8; ++j) dacc[j] = (f32x4){0.f, 0.f, 0.f, 0.f};
    const int qrow = w * 16 + cc;
    #pragma unroll
    for (int kc = 0; kc < 2; ++kc){
        short8 afrag = *(const short8*)&sQ[qrow * 64 + (((kc * 4 + quad) ^ (cc & 7)) * 8)];
        #pragma unroll
        for (int kt = 0; kt < 8; ++kt){
            int krow = kt * 16 + cc;
            short8 bfrag = *(const short8*)&sQ[krow * 64 + (((kc * 4 + quad) ^ (cc & 7)) * 8)];
            dacc[kt] = __builtin_amdgcn_mfma_f32_16x16x32_bf16(afrag, bfrag, dacc[kt], 0, 0, 0);
        }
    }

    // ---- scale + masks + row softmax (rows: q = w*16 + quad*4 + reg) ----
    int bq[4], tq[4];
    #pragma unroll
    for (int r = 0; r < 4; ++r){
        int q = w * 16 + quad * 4 + r;
        bq[r] = s_buck[q]; tq[r] = s_t[q];
    }
    float mrow[4] = {-1e30f, -1e30f, -1e30f, -1e30f};
    #pragma unroll
    for (int kt = 0; kt < 8; ++kt){
        int kk = kt * 16 + cc;
        float inv = s_inv[kk];
        int bk = s_buck[kk], tk = s_t[kk];
        #pragma unroll
        for (int r = 0; r < 4; ++r){
            float d = dacc[kt][r] * inv;
            if (bk != bq[r]) d = -1e9f;
            if (tk == tq[r]) d = -1e-5f;
            dacc[kt][r] = d;
            mrow[r] = fmaxf(mrow[r], d);
        }
    }
    #pragma unroll
    for (int r = 0; r < 4; ++r)
        #pragma unroll
        for (int m = 8; m >= 1; m >>= 1)
            mrow[r] = fmaxf(mrow[r], __shfl_xor(mrow[r], m, 64));
    // exp once: keep p = exp(d - m) in dacc, sum it
    float srow[4] = {0.f, 0.f, 0.f, 0.f};
    #pragma unroll
    for (int kt = 0; kt < 8; ++kt)
        #pragma unroll
        for (int r = 0; r < 4; ++r){
            float e = __expf(dacc[kt][r] - mrow[r]);
            dacc[kt][r] = e;
            srow[r] += e;
        }
    #pragma unroll
    for (int r = 0; r < 4; ++r)
        #pragma unroll
        for (int m = 8; m >= 1; m >>= 1)
            srow[r] += __shfl_xor(srow[r], m, 64);
    float lse[4], pscale[4];
    #pragma unroll
    for (int r = 0; r < 4; ++r){
        lse[r] = mrow[r] + __logf(srow[r]);
        pscale[r] = 1.f / srow[r];
    }
    if (cc == 0){
        #pragma unroll
        for (int r = 0; r < 4; ++r) s_lse[w * 16 + quad * 4 + r] = lse[r];
    }

    // all waves' QK^T reads of sQ must complete before sP overwrites it;
    // barrier placed after softmax so that VALU overlaps slower waves' MFMA.
    __syncthreads();

    // ---- probs -> sP (C-layout scatter into swizzled A-layout tile) ----
    #pragma unroll
    for (int kt = 0; kt < 8; ++kt){
        int kk = kt * 16 + cc;
        #pragma unroll
        for (int r = 0; r < 4; ++r){
            int q = w * 16 + quad * 4 + r;
            sP[q * 128 + (((kk >> 3) ^ (q & 15)) * 8) + (kk & 7)] =
                f2bf(dacc[kt][r] * pscale[r]);
        }
    }
    __syncthreads();

    // ---- PV: wave w -> q-tile w; 4 k-chunks x 4 n-tiles ----
    f32x4 oacc[4];
    #pragma unroll
    for (int j = 0; j < 4; ++j) oacc[j] = (f32x4){0.f, 0.f, 0.f, 0.f};
    #pragma unroll
    for (int kc = 0; kc < 4; ++kc){
        short8 afrag = *(const short8*)&sP[qrow * 128 + (((kc * 4 + quad) ^ cc) * 8)];
        #pragma unroll
        for (int nt = 0; nt < 4; ++nt){
            int d = nt * 16 + cc;
            short8 bfrag = *(const short8*)&sVt[d * 128 + (((kc * 4 + quad) ^ VSWZ(d)) * 8)];
            oacc[nt] = __builtin_amdgcn_mfma_f32_16x16x32_bf16(afrag, bfrag, oacc[nt], 0, 0, 0);
        }
    }

    // ---- epilogue: scatter o (bf16) and logits to per-hash buffers ----
    #pragma unroll
    for (int r = 0; r < 4; ++r){
        int q = w * 16 + quad * 4 + r;
        int si = s_idx[q];
        int jj = si >> 12; int t = si & (T_ - 1);
        size_t base = ((size_t)(hn * NH_ + jj) * T_ + t) * 64;
        #pragma unroll
        for (int nt = 0; nt < 4; ++nt)
            o_hash[base + nt * 16 + cc] = f2bf(oacc[nt][r]);
    }
    if (tid < 64){
        int si = s_idx[tid]; int jj = si >> 12; int t = si & (T_ - 1);
        logit_hash[(size_t)(hn * NH_ + jj) * T_ + t] = s_lse[tid];
    }
}

// ---------------------------------------------------------------------------
// K5: combine over NH hash rounds per head + fused LayerNorm. block = (t,n)
// ---------------------------------------------------------------------------
__global__ __launch_bounds__(256) void k_comb(const u16* __restrict__ o_hash,
        const float* __restrict__ logit_hash, const float* __restrict__ gamma,
        const float* __restrict__ beta, float* __restrict__ out){
    const int t = blockIdx.x, n = blockIdx.y;
    const int tid = threadIdx.x;
    __shared__ float s_pw[32];
    __shared__ float s_x[512];
    __shared__ float s_red[8];
    __shared__ float s_mu, s_rs;
    if (tid < 32){
        int h = tid >> 2, j = tid & 3;
        s_pw[tid] = logit_hash[(size_t)((h * N_ + n) * NH_ + j) * T_ + t];
    }
    __syncthreads();
    if (tid < 8){
        int h = tid;
        float m = -1e30f;
        #pragma unroll
        for (int j = 0; j < 4; ++j) m = fmaxf(m, s_pw[h * 4 + j]);
        float l = 0.f;
        #pragma unroll
        for (int j = 0; j < 4; ++j) l += __expf(s_pw[h * 4 + j] - m);
        float ls = m + __logf(l);
        #pragma unroll
        for (int j = 0; j < 4; ++j) s_pw[h * 4 + j] = __expf(s_pw[h * 4 + j] - ls);
    }
    __syncthreads();
    float va[2];
    #pragma unroll
    for (int i = 0; i < 2; ++i){
        int cidx = tid + i * 256;
        int h = cidx >> 6, d = cidx & 63;
        size_t base = (size_t)((h * N_ + n) * NH_) * T_ * 64;
        float acc = 0.f;
        #pragma unroll
        for (int j = 0; j < 4; ++j)
            acc += s_pw[h * 4 + j] * bf2f(o_hash[base + ((size_t)j * T_ + t) * 64 + d]);
        s_x[cidx] = acc; va[i] = acc;
    }
    float s1 = va[0] + va[1];
    float s2 = va[0] * va[0] + va[1] * va[1];
    #pragma unroll
    for (int m = 32; m >= 1; m >>= 1){
        s1 += __shfl_xor(s1, m, 64);
        s2 += __shfl_xor(s2, m, 64);
    }
    const int lane = tid & 63, w = tid >> 6;
    if (lane == 0){ s_red[w] = s1; s_red[4 + w] = s2; }
    __syncthreads();
    if (tid == 0){
        float S1 = s_red[0] + s_red[1] + s_red[2] + s_red[3];
        float S2 = s_red[4] + s_red[5] + s_red[6] + s_red[7];
        float mu = S1 / 512.f;
        float var = S2 / 512.f - mu * mu;
        s_mu = mu; s_rs = 1.f / sqrtf(var + 1e-3f);
    }
    __syncthreads();
    #pragma unroll
    for (int i = 0; i < 2; ++i){
        int cidx = tid + i * 256;
        out[((size_t)(n * T_ + t)) * 512 + cidx] =
            gamma[cidx] * (s_x[cidx] - s_mu) * s_rs + beta[cidx];
    }
}

// ---------------------------------------------------------------------------
extern "C" void kernel_launch(void* const* d_in, const int* in_sizes, int n_in,
                              void* d_out, int out_size, void* d_ws, size_t ws_size,
                              hipStream_t stream){
    const float* x     = (const float*)d_in[0];
    const float* Wq    = (const float*)d_in[1];
    const float* bq    = (const float*)d_in[2];
    const float* Wv    = (const float*)d_in[3];
    const float* bv    = (const float*)d_in[4];
    const float* gamma = (const float*)d_in[5];
    const float* beta  = (const float*)d_in[6];
    const float* rot   = (const float*)d_in[7];
    char* ws = (char*)d_ws;
    // workspace layout. Q fp32 buffer eliminated (rotation fused into k_q);
    // o_hash [0,67.1MB) is written only by k_attn.
    u16*   o_hash   = (u16*)  (ws + 0);               // 67,108,864 B
    u16*   Qbf      = (u16*)  (ws + 67108864);        // 16,777,216 B
    u16*   Vbf      = (u16*)  (ws + 83886080);        // 16,777,216 B
    float* qinv     = (float*)(ws + 100663296);       //    524,288 B
    int*   buckets  = (int*)  (ws + 101187584);       //  2,097,152 B
    int*   sticker  = (int*)  (ws + 103284736);       //  2,097,152 B
    float* logit    = (float*)(ws + 105381888);       //  2,097,152 B
    int*   hist     = (int*)  (ws + 107479040);       //  2,097,152 B
    int*   bstart   = (int*)  (ws + 109576192);       //     32,768 B
    u16*   xf       = (u16*)  (ws + 109608960);       // 16,777,216 B (dead after k_gemmV)
    u16*   wvt      = (u16*)  (ws + 126386176);       //    524,288 B

    hipLaunchKernelGGL(k_decXf,   dim3(8192),       dim3(256), 0, stream,
                       x, xf);
    hipLaunchKernelGGL(k_decWv,   dim3(16, 16),     dim3(256), 0, stream,
                       Wv, wvt);
    hipLaunchKernelGGL(k_gemmV,   dim3(128, 4),     dim3(256), 0, stream,
                       xf, wvt, bv, Vbf);
    hipLaunchKernelGGL(k_q,       dim3(128, 4),     dim3(512), 0, stream,
                       x, Wq, bq, rot, Qbf, qinv, buckets);
    hipLaunchKernelGGL(k_hist,    dim3(64, 32),     dim3(256), 0, stream,
                       buckets, hist);
    hipLaunchKernelGGL(k_scan,    dim3(32),         dim3(256), 0, stream,
                       hist, bstart);
    hipLaunchKernelGGL(k_scatter, dim3(64, 32),     dim3(256), 0, stream,
                       buckets, hist, bstart, sticker);
    hipLaunchKernelGGL(k_attn,    dim3(256, 4, 8),  dim3(256), 0, stream,
                       Qbf, Vbf, qinv, buckets, sticker, o_hash, logit);
    hipLaunchKernelGGL(k_comb,    dim3(4096, 4),    dim3(256), 0, stream,
                       o_hash, logit, gamma, beta, (float*)d_out);
}

// Round 7
// 380.672 us; speedup vs baseline: 1.0655x; 1.0300x over previous
//
#include <hip/hip_runtime.h>
#include <hip/hip_bf16.h>

#define N_ 4
#define T_ 4096
#define D_ 512
#define H_ 8
#define DH_ 64
#define NH_ 4
#define NB_ 64
#define CS_ 256
#define L_ 16384

typedef unsigned short u16;
typedef unsigned int u32;
typedef __attribute__((ext_vector_type(8))) short short8;
typedef __attribute__((ext_vector_type(8))) _Float16 half8;
typedef __attribute__((ext_vector_type(4))) float f32x4;
typedef __attribute__((ext_vector_type(2))) float f32x2;

__device__ __forceinline__ u16 f2bf(float x){
    union { float f; u32 u; } c; c.f = x;
    u32 u = c.u;
    u32 r = (u + 0x7FFFu + ((u >> 16) & 1u)) >> 16;
    return (u16)r;
}
__device__ __forceinline__ float bf2f(u16 b){
    union { u32 u; float f; } c; c.u = ((u32)b) << 16;
    return c.f;
}
__device__ __forceinline__ u16 f2h(float x){
    _Float16 h = (_Float16)x;
    u16 r; __builtin_memcpy(&r, &h, 2); return r;
}

// packed fp32 FMA: acc.{lo,hi} += a_scalar * b.{lo,hi}
// NOTE (r4 data): half-rate on gfx950 (4 cyc) — win vs scalar is issue-slot
// economy only. k_q FMA-pipe floor ~55us.
#define PK_LO(acc, a, b) \
    asm("v_pk_fma_f32 %0, %1, %2, %0 op_sel:[0,0,0] op_sel_hi:[0,1,1]" \
        : "+v"(acc) : "v"(a), "v"(b))
#define PK_HI(acc, a, b) \
    asm("v_pk_fma_f32 %0, %1, %2, %0 op_sel:[1,0,0] op_sel_hi:[1,1,1]" \
        : "+v"(acc) : "v"(a), "v"(b))

// sVt bank-spread swizzle (r2: fixed 16-way conflict in k_attn V staging)
#define VSWZ(d) ((((d) >> 3) ^ ((d) & 7)))

// ---------------------------------------------------------------------------
// K0b: transpose Wv -> wvt [512 n][512 k] f16
// ---------------------------------------------------------------------------
__global__ __launch_bounds__(256) void k_decWv(const float* __restrict__ Wv,
        u16* __restrict__ wvt){
    __shared__ float tile[32][33];
    const int tid = threadIdx.x;
    const int kt = blockIdx.x * 32, nt = blockIdx.y * 32;
    const int tx = tid & 31, ty = tid >> 5;
    #pragma unroll
    for (int i = 0; i < 4; ++i)
        tile[ty + i * 8][tx] = Wv[(size_t)(kt + ty + i * 8) * 512 + nt + tx];
    __syncthreads();
    #pragma unroll
    for (int i = 0; i < 4; ++i){
        int n = ty + i * 8;
        wvt[(size_t)(nt + n) * 512 + kt + tx] = f2h(tile[tx][n]);
    }
}

// ---------------------------------------------------------------------------
// K1 (ROLE-SPLIT): grid 1024 blocks; role 0 = Q GEMM (r3-proven fp32 VALU
//   kernel, verbatim), role 1 = V GEMM (r3-proven MFMA kernel, verbatim,
//   with x->f16 conversion folded into staging; k_decXf + xf eliminated).
//   Mechanism (m114): VALU-only Q waves and MFMA-only V waves co-resident
//   on one CU overlap fully — merging the two serial dispatches lets V ride
//   the MFMA pipe under Q's VALU time. role=(bid>>8)&1 aims opposite roles
//   at the 2 blocks each CU hosts under round-robin dispatch; worst case
//   (roles segregate) is neutral. Numerics: both paths bit-identical to the
//   separate kernels (same code, same accumulation order, same f2h).
// ---------------------------------------------------------------------------
__global__ __launch_bounds__(512, 4) void k_qv(const float* __restrict__ x,
        const float* __restrict__ Wq, const float* __restrict__ bq,
        const u16* __restrict__ wvt, const float* __restrict__ bv,
        float* __restrict__ Q, u16* __restrict__ Qbf, float* __restrict__ qinv,
        u16* __restrict__ Vbf){
    // union LDS: Q role uses 33792B (2 dbuf fp32 panels); V role 20480B.
    __shared__ __align__(16) char uLDS[33792];

    const int bid = blockIdx.x;
    const int role = (bid >> 8) & 1;
    const int id = ((bid >> 9) << 8) | (bid & 255);   // [0,512) per role
    const int mb = (id & 127) * 128;
    const int nbi = id >> 7;
    const int nb = nbi * 128;
    const int tid = threadIdx.x;

    if (role == 0){
        // ================= Q = x@W_Q + b_Q (fp32, exact-class) ===========
        typedef float (*pan_t)[16][132];
        pan_t sA = (pan_t)uLDS;                       // sA[p][k][m]
        pan_t sB = (pan_t)(uLDS + 16896);             // sB[p][k][n]
        const int tx = tid & 31, ty = tid >> 5;
        f32x2 acc2[8][2];
        #pragma unroll
        for (int i = 0; i < 8; ++i){
            acc2[i][0] = (f32x2){0.f, 0.f};
            acc2[i][1] = (f32x2){0.f, 0.f};
        }
        const int mA = tid >> 2, kA = (tid & 3) * 4;
        const int kB = tid >> 5, cB = (tid & 31) * 4;
        const float* xp = &x[(size_t)(mb + mA) * 512 + kA];
        const float* wp = &Wq[(size_t)kB * 512 + nb + cB];
        float4 pa = *(const float4*)xp;
        float4 pb = *(const float4*)wp;

        for (int k0 = 0; k0 < 512; k0 += 16){
            const int p = (k0 >> 4) & 1;
            sA[p][kA + 0][mA] = pa.x; sA[p][kA + 1][mA] = pa.y;
            sA[p][kA + 2][mA] = pa.z; sA[p][kA + 3][mA] = pa.w;
            *(float4*)&sB[p][kB][cB] = pb;
            __syncthreads();
            if (k0 < 496){
                pa = *(const float4*)(xp + k0 + 16);
                pb = *(const float4*)(wp + (size_t)(k0 + 16) * 512);
            }
            #pragma unroll
            for (int kk = 0; kk < 16; ++kk){
                float4 va0 = *(const float4*)&sA[p][kk][ty * 8];
                float4 va1 = *(const float4*)&sA[p][kk][ty * 8 + 4];
                float4 vb  = *(const float4*)&sB[p][kk][tx * 4];
                f32x2 a2[4], b2[2];
                a2[0] = (f32x2){va0.x, va0.y}; a2[1] = (f32x2){va0.z, va0.w};
                a2[2] = (f32x2){va1.x, va1.y}; a2[3] = (f32x2){va1.z, va1.w};
                b2[0] = (f32x2){vb.x, vb.y};   b2[1] = (f32x2){vb.z, vb.w};
                #pragma unroll
                for (int i = 0; i < 8; ++i){
                    if (i & 1){
                        PK_HI(acc2[i][0], a2[i >> 1], b2[0]);
                        PK_HI(acc2[i][1], a2[i >> 1], b2[1]);
                    } else {
                        PK_LO(acc2[i][0], a2[i >> 1], b2[0]);
                        PK_LO(acc2[i][1], a2[i >> 1], b2[1]);
                    }
                }
            }
            // no trailing barrier: next iteration writes the other buffer
        }

        float4 vbq = *(const float4*)&bq[nb + tx * 4];
        const int h = nbi * 2 + (tx >> 4);
        const int d0 = (tx & 15) * 4;
        #pragma unroll
        for (int i = 0; i < 8; ++i){
            float o0 = acc2[i][0].x + vbq.x;
            float o1 = acc2[i][0].y + vbq.y;
            float o2 = acc2[i][1].x + vbq.z;
            float o3 = acc2[i][1].y + vbq.w;
            int m = mb + ty * 8 + i;
            int n = m >> 12, t = m & (T_ - 1);
            float4 q4; q4.x = o0; q4.y = o1; q4.z = o2; q4.w = o3;
            *(float4*)&Q[(size_t)m * 512 + nb + tx * 4] = q4;
            float ss = o0 * o0 + o1 * o1 + o2 * o2 + o3 * o3;
            #pragma unroll
            for (int s = 8; s >= 1; s >>= 1) ss += __shfl_xor(ss, s, 64);
            size_t rowb = (size_t)(h * N_ + n) * T_ + t;
            if ((tx & 15) == 0) qinv[rowb] = 1.f / (sqrtf(ss) + 1e-6f);
            ushort4 qb4;
            qb4.x = f2bf(o0); qb4.y = f2bf(o1); qb4.z = f2bf(o2); qb4.w = f2bf(o3);
            *(ushort4*)&Qbf[rowb * 64 + d0] = qb4;
        }
    } else {
        // ================= V = x@W_V + b_V (f16 MFMA) ====================
        if (tid >= 256) return;        // exited waves don't hold s_barrier
        u16* sA = (u16*)uLDS;                         // [128*40]
        u16* sB = (u16*)(uLDS + 10240);               // [128*40]
        const int w = tid >> 6, lane = tid & 63;
        const int quad = lane >> 4, cc = lane & 15;
        const int wm = (w & 1) * 64, wn = (w >> 1) * 64;
        f32x4 acc[4][4];
        #pragma unroll
        for (int i = 0; i < 4; ++i)
            #pragma unroll
            for (int j = 0; j < 4; ++j) acc[i][j] = (f32x4){0.f, 0.f, 0.f, 0.f};

        for (int k0 = 0; k0 < 512; k0 += 32){
            #pragma unroll
            for (int i = 0; i < 2; ++i){
                int idx = i * 256 + tid;               // 0..511
                int m = idx >> 2, ks = idx & 3;
                const float* xs = &x[(size_t)(mb + m) * 512 + k0 + ks * 8];
                float4 f0 = *(const float4*)xs;
                float4 f1 = *(const float4*)(xs + 4);
                short8 s;                               // == k_decXf's f2h
                s[0] = (short)f2h(f0.x); s[1] = (short)f2h(f0.y);
                s[2] = (short)f2h(f0.z); s[3] = (short)f2h(f0.w);
                s[4] = (short)f2h(f1.x); s[5] = (short)f2h(f1.y);
                s[6] = (short)f2h(f1.z); s[7] = (short)f2h(f1.w);
                *(short8*)&sA[m * 40 + ks * 8] = s;
                *(short8*)&sB[m * 40 + ks * 8] =
                    *(const short8*)&wvt[(size_t)(nb + m) * 512 + k0 + ks * 8];
            }
            __syncthreads();
            half8 a[4], b[4];
            #pragma unroll
            for (int i = 0; i < 4; ++i){
                a[i] = *(const half8*)&sA[(wm + i * 16 + cc) * 40 + quad * 8];
                b[i] = *(const half8*)&sB[(wn + i * 16 + cc) * 40 + quad * 8];
            }
            #pragma unroll
            for (int i = 0; i < 4; ++i)
                #pragma unroll
                for (int j = 0; j < 4; ++j)
                    acc[i][j] = __builtin_amdgcn_mfma_f32_16x16x32_f16(a[i], b[j], acc[i][j], 0, 0, 0);
            __syncthreads();
        }
        #pragma unroll
        for (int i = 0; i < 4; ++i)
            #pragma unroll
            for (int j = 0; j < 4; ++j){
                int c = nb + wn + j * 16 + cc;
                int hh = c >> 6, d = c & 63;
                float bi = bv[c];
                #pragma unroll
                for (int r = 0; r < 4; ++r){
                    int m = mb + wm + i * 16 + quad * 4 + r;
                    int n = m >> 12, t = m & (T_ - 1);
                    Vbf[((size_t)(hh * N_ + n) * T_ + t) * 64 + d] = f2bf(acc[i][j][r] + bi);
                }
            }
    }
}

// ---------------------------------------------------------------------------
// K2: rotations + argmax -> buckets[h][n][j*T + t]  (fp32, exact tie rules)
// ---------------------------------------------------------------------------
__global__ __launch_bounds__(256) void k_rot(const float* __restrict__ Q,
        const float* __restrict__ rot, int* __restrict__ buckets){
    const int tb = blockIdx.x * 32;
    const int n = blockIdx.y, h = blockIdx.z;
    const int hn = h * N_ + n;
    __shared__ float Rs[64 * 128];    // [f][i][jj]: f*128 + i*4 + jj
    __shared__ float Qs[32][64];
    const int tid = threadIdx.x;
    const float* rh = rot + (size_t)h * (64 * 128);   // [f][jj][i] contiguous
    for (int idx = tid; idx < 8192; idx += 256){
        int f = idx >> 7, rem = idx & 127, jj = rem >> 5, i2 = rem & 31;
        Rs[f * 128 + i2 * 4 + jj] = rh[idx];
    }
    for (int i = tid; i < 2048; i += 256){
        int t = i >> 6, f = i & 63;
        Qs[t][f] = Q[(size_t)(n * T_ + tb + t) * 512 + h * 64 + f];
    }
    __syncthreads();
    const int tx = tid & 31, tg = tid >> 5;   // tg: 8 groups of 4 t's
    f32x2 r2[4][2];                            // [tt][jj-pair]
    #pragma unroll
    for (int tt = 0; tt < 4; ++tt){
        r2[tt][0] = (f32x2){0.f, 0.f};
        r2[tt][1] = (f32x2){0.f, 0.f};
    }
    for (int f = 0; f < 64; f += 2){
        f32x2 qf[4];
        #pragma unroll
        for (int tt = 0; tt < 4; ++tt)
            qf[tt] = *(const f32x2*)&Qs[tg * 4 + tt][f];   // (q[f], q[f+1])
        float4 rv0 = *(const float4*)&Rs[f * 128 + tx * 4];
        float4 rv1 = *(const float4*)&Rs[(f + 1) * 128 + tx * 4];
        f32x2 b0[2], b1[2];
        b0[0] = (f32x2){rv0.x, rv0.y}; b0[1] = (f32x2){rv0.z, rv0.w};
        b1[0] = (f32x2){rv1.x, rv1.y}; b1[1] = (f32x2){rv1.z, rv1.w};
        #pragma unroll
        for (int tt = 0; tt < 4; ++tt){
            PK_LO(r2[tt][0], qf[tt], b0[0]);   // f   contribution
            PK_LO(r2[tt][1], qf[tt], b0[1]);
            PK_HI(r2[tt][0], qf[tt], b1[0]);   // f+1 contribution
            PK_HI(r2[tt][1], qf[tt], b1[1]);
        }
    }
    #pragma unroll
    for (int tt = 0; tt < 4; ++tt){
        #pragma unroll
        for (int jj = 0; jj < 4; ++jj){
            float rval = (jj < 2) ? r2[tt][0][jj] : r2[tt][1][jj - 2];
            // argmax over concat(r, -r); first-occurrence tie-break
            float bv = rval; int bi = tx;
            float nv = -bv;
            if (nv > bv){ bv = nv; bi = 32 + tx; }
            #pragma unroll
            for (int m = 16; m >= 1; m >>= 1){
                float ov = __shfl_xor(bv, m, 32);
                int   oi = __shfl_xor(bi, m, 32);
                if (ov > bv || (ov == bv && oi < bi)){ bv = ov; bi = oi; }
            }
            if (tx == 0){
                int t = tb + tg * 4 + tt;
                buckets[(size_t)hn * L_ + jj * T_ + t] = bi + jj * 64;
            }
        }
    }
}

// ---------------------------------------------------------------------------
// K3a: per-(hn,tile) 256-bin histogram. tile = 256 consecutive items.
// ---------------------------------------------------------------------------
__global__ __launch_bounds__(256) void k_hist(const int* __restrict__ buckets,
        int* __restrict__ hist){
    const int tile = blockIdx.x, hn = blockIdx.y;
    const int tid = threadIdx.x;
    __shared__ int h[256];
    h[tid] = 0;
    __syncthreads();
    int b = buckets[(size_t)hn * L_ + tile * 256 + tid];
    atomicAdd(&h[b], 1);
    __syncthreads();
    hist[((size_t)hn * 64 + tile) * 256 + tid] = h[tid];
}

// ---------------------------------------------------------------------------
// K3b: per-hn: in-place exclusive prefix of hist over tiles (per bucket),
//      then block scan of bucket totals -> bucketStart[hn][256]
// ---------------------------------------------------------------------------
__global__ __launch_bounds__(256) void k_scan(int* __restrict__ hist,
        int* __restrict__ bucketStart){
    const int hn = blockIdx.x;
    const int b = threadIdx.x;
    int* hh = hist + (size_t)hn * 64 * 256;
    int run = 0;
    for (int tl = 0; tl < 64; ++tl){
        int v = hh[tl * 256 + b];
        hh[tl * 256 + b] = run;      // exclusive within-bucket tile prefix
        run += v;
    }
    __shared__ int s[256];
    s[b] = run;
    __syncthreads();
    for (int off = 1; off < 256; off <<= 1){
        int add = (b >= off) ? s[b - off] : 0;
        __syncthreads();
        s[b] += add;
        __syncthreads();
    }
    bucketStart[hn * 256 + b] = s[b] - run;   // exclusive bucket start
}

// ---------------------------------------------------------------------------
// K3c: stable scatter: sticker[pos] = item index
// ---------------------------------------------------------------------------
__global__ __launch_bounds__(256) void k_scatter(const int* __restrict__ buckets,
        const int* __restrict__ offs, const int* __restrict__ bucketStart,
        int* __restrict__ sticker){
    const int tile = blockIdx.x, hn = blockIdx.y;
    const int tid = threadIdx.x;
    __shared__ int sb[256];
    const int i = tile * 256 + tid;
    const int b = buckets[(size_t)hn * L_ + i];
    sb[tid] = b;
    __syncthreads();
    int rank = 0;
    #pragma unroll 8
    for (int j = 0; j < 256; ++j){
        int v = sb[j];                         // broadcast read
        rank += (j < tid && v == b) ? 1 : 0;
    }
    int pos = bucketStart[hn * 256 + b]
            + offs[((size_t)hn * 64 + tile) * 256 + b]
            + rank;
    sticker[(size_t)hn * L_ + pos] = i;
}

// ---------------------------------------------------------------------------
// K4: chunked attention via MFMA. block = (chunk, n, h). 64 q x 128 k, DH=64
//     sP aliases sQ (dead after QK^T) -> ~34.5KB LDS -> 4 blocks/CU.
// ---------------------------------------------------------------------------
__global__ __launch_bounds__(256) void k_attn(const u16* __restrict__ Qbf,
        const u16* __restrict__ Vbf, const float* __restrict__ qinv,
        const int* __restrict__ buckets, const int* __restrict__ sticker,
        u16* __restrict__ o_hash, float* __restrict__ logit_hash){
    const int blk_c = blockIdx.x, n = blockIdx.y, h = blockIdx.z;
    const int hn = h * N_ + n;
    const int tid = threadIdx.x;
    const int w = tid >> 6, lane = tid & 63;
    const int quad = lane >> 4, cc = lane & 15;

    __shared__ __align__(16) u16 sQP[128 * 64];
    __shared__ __align__(16) u16 sVt[64 * 128];   // row = d, col = key row (V^T)
    __shared__ int s_idx[128], s_buck[128], s_t[128];
    __shared__ float s_inv[128];
    __shared__ float s_lse[64];
    u16* const sQ = sQP;
    u16* const sP = sQP;

    if (tid < 128){
        int cprev = (blk_c + CS_ - 1) & (CS_ - 1);
        int pos = (tid < 64) ? blk_c * 64 + tid : cprev * 64 + (tid - 64);
        int idx = sticker[(size_t)hn * L_ + pos];
        s_idx[tid] = idx;
        s_buck[tid] = buckets[(size_t)hn * L_ + idx];
        int t = idx & (T_ - 1);
        s_t[tid] = t;
        s_inv[tid] = qinv[(size_t)hn * T_ + t] * 0.125f;   // exact pow2 fold
    }
    __syncthreads();

    // ---- stage Q rows (b128) and V transposed (scalar b16) ----
    const int r0 = tid >> 3, l8 = tid & 7;
    #pragma unroll
    for (int it = 0; it < 4; ++it){
        int r = it * 32 + r0;
        size_t gb = ((size_t)hn * T_ + s_t[r]) * 64 + l8 * 8;
        short8 qv = *(const short8*)&Qbf[gb];
        *(short8*)&sQ[r * 64 + ((l8 ^ (r & 7)) * 8)] = qv;
        short8 vv = *(const short8*)&Vbf[gb];
        #pragma unroll
        for (int i = 0; i < 8; ++i){
            int d = l8 * 8 + i;
            sVt[d * 128 + (((r >> 3) ^ VSWZ(d)) * 8) + (r & 7)] = (u16)vv[i];
        }
    }
    __syncthreads();

    // ---- QK^T: wave w -> q-tile w; 2 k-chunks x 8 k-tiles ----
    f32x4 dacc[8];
    #pragma unroll
    for (int j = 0; j < 8; ++j) dacc[j] = (f32x4){0.f, 0.f, 0.f, 0.f};
    const int qrow = w * 16 + cc;
    #pragma unroll
    for (int kc = 0; kc < 2; ++kc){
        short8 afrag = *(const short8*)&sQ[qrow * 64 + (((kc * 4 + quad) ^ (cc & 7)) * 8)];
        #pragma unroll
        for (int kt = 0; kt < 8; ++kt){
            int krow = kt * 16 + cc;
            short8 bfrag = *(const short8*)&sQ[krow * 64 + (((kc * 4 + quad) ^ (cc & 7)) * 8)];
            dacc[kt] = __builtin_amdgcn_mfma_f32_16x16x32_bf16(afrag, bfrag, dacc[kt], 0, 0, 0);
        }
    }

    // ---- scale + masks + row softmax (rows: q = w*16 + quad*4 + reg) ----
    int bq[4], tq[4];
    #pragma unroll
    for (int r = 0; r < 4; ++r){
        int q = w * 16 + quad * 4 + r;
        bq[r] = s_buck[q]; tq[r] = s_t[q];
    }
    float mrow[4] = {-1e30f, -1e30f, -1e30f, -1e30f};
    #pragma unroll
    for (int kt = 0; kt < 8; ++kt){
        int kk = kt * 16 + cc;
        float inv = s_inv[kk];
        int bk = s_buck[kk], tk = s_t[kk];
        #pragma unroll
        for (int r = 0; r < 4; ++r){
            float d = dacc[kt][r] * inv;
            if (bk != bq[r]) d = -1e9f;
            if (tk == tq[r]) d = -1e-5f;
            dacc[kt][r] = d;
            mrow[r] = fmaxf(mrow[r], d);
        }
    }
    #pragma unroll
    for (int r = 0; r < 4; ++r)
        #pragma unroll
        for (int m = 8; m >= 1; m >>= 1)
            mrow[r] = fmaxf(mrow[r], __shfl_xor(mrow[r], m, 64));
    // exp once: keep p = exp(d - m) in dacc, sum it
    float srow[4] = {0.f, 0.f, 0.f, 0.f};
    #pragma unroll
    for (int kt = 0; kt < 8; ++kt)
        #pragma unroll
        for (int r = 0; r < 4; ++r){
            float e = __expf(dacc[kt][r] - mrow[r]);
            dacc[kt][r] = e;
            srow[r] += e;
        }
    #pragma unroll
    for (int r = 0; r < 4; ++r)
        #pragma unroll
        for (int m = 8; m >= 1; m >>= 1)
            srow[r] += __shfl_xor(srow[r], m, 64);
    float lse[4], pscale[4];
    #pragma unroll
    for (int r = 0; r < 4; ++r){
        lse[r] = mrow[r] + __logf(srow[r]);
        pscale[r] = 1.f / srow[r];
    }
    if (cc == 0){
        #pragma unroll
        for (int r = 0; r < 4; ++r) s_lse[w * 16 + quad * 4 + r] = lse[r];
    }

    // all waves' QK^T reads of sQ must complete before sP overwrites it;
    // barrier placed after softmax so that VALU overlaps slower waves' MFMA.
    __syncthreads();

    // ---- probs -> sP (C-layout scatter into swizzled A-layout tile) ----
    #pragma unroll
    for (int kt = 0; kt < 8; ++kt){
        int kk = kt * 16 + cc;
        #pragma unroll
        for (int r = 0; r < 4; ++r){
            int q = w * 16 + quad * 4 + r;
            sP[q * 128 + (((kk >> 3) ^ (q & 15)) * 8) + (kk & 7)] =
                f2bf(dacc[kt][r] * pscale[r]);
        }
    }
    __syncthreads();

    // ---- PV: wave w -> q-tile w; 4 k-chunks x 4 n-tiles ----
    f32x4 oacc[4];
    #pragma unroll
    for (int j = 0; j < 4; ++j) oacc[j] = (f32x4){0.f, 0.f, 0.f, 0.f};
    #pragma unroll
    for (int kc = 0; kc < 4; ++kc){
        short8 afrag = *(const short8*)&sP[qrow * 128 + (((kc * 4 + quad) ^ cc) * 8)];
        #pragma unroll
        for (int nt = 0; nt < 4; ++nt){
            int d = nt * 16 + cc;
            short8 bfrag = *(const short8*)&sVt[d * 128 + (((kc * 4 + quad) ^ VSWZ(d)) * 8)];
            oacc[nt] = __builtin_amdgcn_mfma_f32_16x16x32_bf16(afrag, bfrag, oacc[nt], 0, 0, 0);
        }
    }

    // ---- epilogue: scatter o (bf16) and logits to per-hash buffers ----
    #pragma unroll
    for (int r = 0; r < 4; ++r){
        int q = w * 16 + quad * 4 + r;
        int si = s_idx[q];
        int jj = si >> 12; int t = si & (T_ - 1);
        size_t base = ((size_t)(hn * NH_ + jj) * T_ + t) * 64;
        #pragma unroll
        for (int nt = 0; nt < 4; ++nt)
            o_hash[base + nt * 16 + cc] = f2bf(oacc[nt][r]);
    }
    if (tid < 64){
        int si = s_idx[tid]; int jj = si >> 12; int t = si & (T_ - 1);
        logit_hash[(size_t)(hn * NH_ + jj) * T_ + t] = s_lse[tid];
    }
}

// ---------------------------------------------------------------------------
// K5: combine over NH hash rounds per head + fused LayerNorm. block = (t,n)
// ---------------------------------------------------------------------------
__global__ __launch_bounds__(256) void k_comb(const u16* __restrict__ o_hash,
        const float* __restrict__ logit_hash, const float* __restrict__ gamma,
        const float* __restrict__ beta, float* __restrict__ out){
    const int t = blockIdx.x, n = blockIdx.y;
    const int tid = threadIdx.x;
    __shared__ float s_pw[32];
    __shared__ float s_x[512];
    __shared__ float s_red[8];
    __shared__ float s_mu, s_rs;
    if (tid < 32){
        int h = tid >> 2, j = tid & 3;
        s_pw[tid] = logit_hash[(size_t)((h * N_ + n) * NH_ + j) * T_ + t];
    }
    __syncthreads();
    if (tid < 8){
        int h = tid;
        float m = -1e30f;
        #pragma unroll
        for (int j = 0; j < 4; ++j) m = fmaxf(m, s_pw[h * 4 + j]);
        float l = 0.f;
        #pragma unroll
        for (int j = 0; j < 4; ++j) l += __expf(s_pw[h * 4 + j] - m);
        float ls = m + __logf(l);
        #pragma unroll
        for (int j = 0; j < 4; ++j) s_pw[h * 4 + j] = __expf(s_pw[h * 4 + j] - ls);
    }
    __syncthreads();
    float va[2];
    #pragma unroll
    for (int i = 0; i < 2; ++i){
        int cidx = tid + i * 256;
        int h = cidx >> 6, d = cidx & 63;
        size_t base = (size_t)((h * N_ + n) * NH_) * T_ * 64;
        float acc = 0.f;
        #pragma unroll
        for (int j = 0; j < 4; ++j)
            acc += s_pw[h * 4 + j] * bf2f(o_hash[base + ((size_t)j * T_ + t) * 64 + d]);
        s_x[cidx] = acc; va[i] = acc;
    }
    float s1 = va[0] + va[1];
    float s2 = va[0] * va[0] + va[1] * va[1];
    #pragma unroll
    for (int m = 32; m >= 1; m >>= 1){
        s1 += __shfl_xor(s1, m, 64);
        s2 += __shfl_xor(s2, m, 64);
    }
    const int lane = tid & 63, w = tid >> 6;
    if (lane == 0){ s_red[w] = s1; s_red[4 + w] = s2; }
    __syncthreads();
    if (tid == 0){
        float S1 = s_red[0] + s_red[1] + s_red[2] + s_red[3];
        float S2 = s_red[4] + s_red[5] + s_red[6] + s_red[7];
        float mu = S1 / 512.f;
        float var = S2 / 512.f - mu * mu;
        s_mu = mu; s_rs = 1.f / sqrtf(var + 1e-3f);
    }
    __syncthreads();
    #pragma unroll
    for (int i = 0; i < 2; ++i){
        int cidx = tid + i * 256;
        out[((size_t)(n * T_ + t)) * 512 + cidx] =
            gamma[cidx] * (s_x[cidx] - s_mu) * s_rs + beta[cidx];
    }
}

// ---------------------------------------------------------------------------
extern "C" void kernel_launch(void* const* d_in, const int* in_sizes, int n_in,
                              void* d_out, int out_size, void* d_ws, size_t ws_size,
                              hipStream_t stream){
    const float* x     = (const float*)d_in[0];
    const float* Wq    = (const float*)d_in[1];
    const float* bq    = (const float*)d_in[2];
    const float* Wv    = (const float*)d_in[3];
    const float* bv    = (const float*)d_in[4];
    const float* gamma = (const float*)d_in[5];
    const float* beta  = (const float*)d_in[6];
    const float* rot   = (const float*)d_in[7];
    char* ws = (char*)d_ws;
    // workspace layout. Time-disjoint overlap: Q fp32 [0,33.5MB) dead after
    // k_rot; o_hash [0,67.1MB) written only by k_attn (later in stream).
    float* Q        = (float*)(ws + 0);               // 33,554,432 B (k_qv..k_rot)
    u16*   o_hash   = (u16*)  (ws + 0);               // 67,108,864 B (k_attn..k_comb)
    u16*   Qbf      = (u16*)  (ws + 67108864);        // 16,777,216 B
    u16*   Vbf      = (u16*)  (ws + 83886080);        // 16,777,216 B
    float* qinv     = (float*)(ws + 100663296);       //    524,288 B
    int*   buckets  = (int*)  (ws + 101187584);       //  2,097,152 B
    int*   sticker  = (int*)  (ws + 103284736);       //  2,097,152 B
    float* logit    = (float*)(ws + 105381888);       //  2,097,152 B
    int*   hist     = (int*)  (ws + 107479040);       //  2,097,152 B
    int*   bstart   = (int*)  (ws + 109576192);       //     32,768 B
    u16*   wvt      = (u16*)  (ws + 109608960);       //    524,288 B

    hipLaunchKernelGGL(k_decWv,   dim3(16, 16),     dim3(256), 0, stream,
                       Wv, wvt);
    hipLaunchKernelGGL(k_qv,      dim3(1024),       dim3(512), 0, stream,
                       x, Wq, bq, wvt, bv, Q, Qbf, qinv, Vbf);
    hipLaunchKernelGGL(k_rot,     dim3(128, 4, 8),  dim3(256), 0, stream,
                       Q, rot, buckets);
    hipLaunchKernelGGL(k_hist,    dim3(64, 32),     dim3(256), 0, stream,
                       buckets, hist);
    hipLaunchKernelGGL(k_scan,    dim3(32),         dim3(256), 0, stream,
                       hist, bstart);
    hipLaunchKernelGGL(k_scatter, dim3(64, 32),     dim3(256), 0, stream,
                       buckets, hist, bstart, sticker);
    hipLaunchKernelGGL(k_attn,    dim3(256, 4, 8),  dim3(256), 0, stream,
                       Qbf, Vbf, qinv, buckets, sticker, o_hash, logit);
    hipLaunchKernelGGL(k_comb,    dim3(4096, 4),    dim3(256), 0, stream,
                       o_hash, logit, gamma, beta, (float*)d_out);
}